// Round 3
// baseline (6738.512 us; speedup 1.0000x reference)
//
#include <hip/hip_runtime.h>
#include <hip/hip_bf16.h>
#include <math.h>

#define HID 256
#define BSZ 64
#define TLEN 256
#define INW 64
#define OUTW 32
#define NOISE_STD 0.05f
#define TAU 0.2f

typedef __attribute__((ext_vector_type(8))) short short8;
typedef __attribute__((ext_vector_type(4))) float floatx4;

// ---------------------------------------------------------------------------
// one-time: convert W [j][i][k] fp32 -> bf16, swizzled into MFMA B-fragment
// order. B[k][n=i] fragment for (j, kk, ni): lane l holds 8 elems
//   W[j][ i = ni*16 + (l&15) ][ k = kk*32 + (l>>4)*8 + e ],  e=0..7
// flat: Wsw[ (((j*8+kk)*16+ni)*64+l)*8 + e ]
// ---------------------------------------------------------------------------
__global__ __launch_bounds__(256) void swizzle_kernel(const float* __restrict__ W,
                                                      __hip_bfloat16* __restrict__ Wsw) {
    int g = blockIdx.x * 256 + threadIdx.x;      // 0 .. 2^21-1
    int l  = g & 63;
    int ni = (g >> 6) & 15;
    int kk = (g >> 10) & 7;
    int j  = g >> 13;
    int i  = ni * 16 + (l & 15);
    int k0 = kk * 32 + (l >> 4) * 8;
    const float* __restrict__ src = W + ((size_t)j * HID + i) * HID + k0;
    __hip_bfloat16* __restrict__ dst = Wsw + (size_t)g * 8;
#pragma unroll
    for (int e = 0; e < 8; ++e) dst[e] = __float2bfloat16(src[e]);
}

// ---------------------------------------------------------------------------
// init: rbf0 = bf16(tanh(x0))
// ---------------------------------------------------------------------------
__global__ __launch_bounds__(256) void init_kernel(const float* __restrict__ x0,
                                                   __hip_bfloat16* __restrict__ rbf) {
    int idx = blockIdx.x * 256 + threadIdx.x;    // 0..16383
    rbf[idx] = __float2bfloat16(tanhf(x0[idx]));
}

// ---------------------------------------------------------------------------
// persistent kernel: block j (256 blocks = 1 per CU, forced by 132 KB LDS).
// W slice staged to LDS once; all 256 timesteps run inside with a
// device-scope counter barrier per step. x[b][j] lives in registers.
// ---------------------------------------------------------------------------
__global__ __launch_bounds__(256, 1) void persist_kernel(
    const __hip_bfloat16* __restrict__ Wsw,   // swizzled [j][kk][ni][lane][8]
    const float* __restrict__ w_hh,           // [HID][HID]
    const float* __restrict__ u,              // [B][T][IN]
    const float* __restrict__ w_in_w,         // [HID][IN]
    const float* __restrict__ w_in_b,         // [HID]
    const float* __restrict__ noise,          // [T][B][HID]
    const float* __restrict__ x0,             // [B][HID]
    __hip_bfloat16* __restrict__ rb0,         // [B][HID] bf16 (t even reads)
    __hip_bfloat16* __restrict__ rb1,         // [B][HID] bf16 (t odd reads)
    float* __restrict__ traj,                 // [B][T][HID]
    float* __restrict__ xfinal,               // [B][HID]
    int* cnt) {                               // grid barrier counter (zeroed)
    __shared__ short Wlds[65536];             // 128 KB: per-j W slice, frag order
    __shared__ float redw[4][64];

    const int tid  = threadIdx.x;
    const int j    = blockIdx.x;
    const int w    = tid >> 6;
    const int lane = tid & 63;
    const int quad = lane >> 4;
    const int col  = lane & 15;

    // ---- stage W slice (once) ----
    {
        const short* __restrict__ src = (const short*)Wsw + (size_t)j * 65536;
#pragma unroll
        for (int m = 0; m < 32; ++m) {
            int i8 = m * 256 + tid;
            *(short8*)&Wlds[i8 * 8] = *(const short8*)&src[(size_t)i8 * 8];
        }
    }
    float xb = 0.f;
    if (tid < BSZ) xb = x0[tid * HID + j];
    __syncthreads();

#pragma unroll 1
    for (int t = 0; t < TLEN; ++t) {
        const short* __restrict__ cur = (const short*)((t & 1) ? rb1 : rb0);
        __hip_bfloat16* __restrict__ nxt = (t & 1) ? rb0 : rb1;

        // ---- GEMM: P[b,i] = sum_k r[b,k] * W[j,i,k] ----
        floatx4 acc[4][4];
#pragma unroll
        for (int mb = 0; mb < 4; ++mb)
#pragma unroll
            for (int nj = 0; nj < 4; ++nj) acc[mb][nj] = (floatx4){0.f, 0.f, 0.f, 0.f};

#pragma unroll
        for (int kk = 0; kk < 8; ++kk) {
            short8 afrag[4];
#pragma unroll
            for (int mb = 0; mb < 4; ++mb)
                afrag[mb] = *(const short8*)(cur + ((mb * 16 + col) * HID + kk * 32 + quad * 8));
#pragma unroll
            for (int nj = 0; nj < 4; ++nj) {
                short8 bfrag = *(const short8*)&Wlds[((kk * 16 + (w * 4 + nj)) * 64 + lane) * 8];
#pragma unroll
                for (int mb = 0; mb < 4; ++mb)
                    acc[mb][nj] = __builtin_amdgcn_mfma_f32_16x16x32_bf16(
                        afrag[mb], bfrag, acc[mb][nj], 0, 0, 0);
            }
        }

        // ---- epilogue: part[b] = sum_i r[b,i]*(P[b,i] + w_hh[j,i]) ----
        float part[16];
#pragma unroll
        for (int p = 0; p < 16; ++p) part[p] = 0.f;

#pragma unroll
        for (int nj = 0; nj < 4; ++nj) {
            int i = (w * 4 + nj) * 16 + col;
            float whh = w_hh[j * HID + i];
#pragma unroll
            for (int mb = 0; mb < 4; ++mb) {
#pragma unroll
                for (int reg = 0; reg < 4; ++reg) {
                    int b = mb * 16 + quad * 4 + reg;
                    float val = acc[mb][nj][reg] + whh;
                    float rv = __bfloat162float(((const __hip_bfloat16*)cur)[b * HID + i]);
                    part[mb * 4 + reg] = fmaf(rv, val, part[mb * 4 + reg]);
                }
            }
        }
#pragma unroll
        for (int s = 1; s < 16; s <<= 1) {
#pragma unroll
            for (int p = 0; p < 16; ++p) part[p] += __shfl_xor(part[p], s, 64);
        }
        if (col == 0) {
#pragma unroll
            for (int mb = 0; mb < 4; ++mb)
#pragma unroll
                for (int reg = 0; reg < 4; ++reg)
                    redw[w][mb * 16 + quad * 4 + reg] = part[mb * 4 + reg];
        }
        __syncthreads();

        if (tid < BSZ) {
            const int b = tid;
            float rec = redw[0][b] + redw[1][b] + redw[2][b] + redw[3][b];

            float isum = w_in_b[j];
            const float4* __restrict__ urow =
                (const float4*)(u + ((size_t)b * TLEN + t) * INW);
            const float4* __restrict__ wrow = (const float4*)(w_in_w + (size_t)j * INW);
#pragma unroll
            for (int q = 0; q < INW / 4; ++q) {
                float4 uu = urow[q], ww = wrow[q];
                isum = fmaf(uu.x, ww.x, isum);
                isum = fmaf(uu.y, ww.y, isum);
                isum = fmaf(uu.z, ww.z, isum);
                isum = fmaf(uu.w, ww.w, isum);
            }
            rec += isum;

            float nz = noise[((size_t)t * BSZ + b) * HID + j];
            float xn = xb + NOISE_STD * nz + TAU * (rec - xb);
            xb = xn;
            traj[((size_t)b * TLEN + t) * HID + j] = xn;
            if (t == TLEN - 1) {
                xfinal[b * HID + j] = xn;
            } else {
                nxt[b * HID + j] = __float2bfloat16(tanhf(xn));
            }
        }

        // ---- grid barrier (skip after final step) ----
        if (t < TLEN - 1) {
            __syncthreads();   // all waves done reading cur/redw (WAR safety)
            if (tid == 0) {
                __threadfence();            // release: r stores agent-visible
                atomicAdd(cnt, 1);          // device-scope by default
                const int target = (t + 1) * 256;
                while (__hip_atomic_load(cnt, __ATOMIC_RELAXED,
                                         __HIP_MEMORY_SCOPE_AGENT) < target)
                    __builtin_amdgcn_s_sleep(1);
                __threadfence();            // acquire: invalidate stale caches
            }
            __syncthreads();
        }
    }
}

// ---------------------------------------------------------------------------
// output[b,t,o] = w_out_b[o] + sum_h tanh(traj[b,t,h]) * w_out_w[o,h]
// ---------------------------------------------------------------------------
__global__ __launch_bounds__(256) void output_kernel(
    const float* __restrict__ traj,     // [B][T][HID]
    const float* __restrict__ w_out_w,  // [OUT][HID]
    const float* __restrict__ w_out_b,  // [OUT]
    float* __restrict__ out) {          // [B][T][OUT]
    __shared__ float th[8][HID + 1];
    const int bt0 = blockIdx.x * 8;
    const int tid = threadIdx.x;
#pragma unroll
    for (int m = 0; m < 8; ++m) {
        int idx = m * 256 + tid;
        th[idx >> 8][idx & 255] = tanhf(traj[(size_t)bt0 * HID + idx]);
    }
    __syncthreads();
    const int row = tid >> 5, o = tid & 31;
    const float* __restrict__ wrow = w_out_w + (size_t)o * HID;
    float s = w_out_b[o];
#pragma unroll 8
    for (int h = 0; h < HID; ++h) s = fmaf(th[row][h], wrow[h], s);
    out[(size_t)(bt0 + row) * OUTW + o] = s;
}

// ---------------------------------------------------------------------------
extern "C" void kernel_launch(void* const* d_in, const int* in_sizes, int n_in,
                              void* d_out, int out_size, void* d_ws, size_t ws_size,
                              hipStream_t stream) {
    const float* u       = (const float*)d_in[0];  // [B][T][IN]
    const float* x0      = (const float*)d_in[1];  // [B][HID]
    const float* noise   = (const float*)d_in[2];  // [T][B][HID]
    const float* w_hh    = (const float*)d_in[3];  // [HID][HID]
    const float* W       = (const float*)d_in[4];  // [HID][HID][HID]
    const float* w_in_w  = (const float*)d_in[5];  // [HID][IN]
    const float* w_in_b  = (const float*)d_in[6];  // [HID]
    const float* w_out_w = (const float*)d_in[7];  // [OUT][HID]
    const float* w_out_b = (const float*)d_in[8];  // [OUT]

    float* out    = (float*)d_out;                     // [B][T][OUT]
    float* xfinal = out + (size_t)BSZ * TLEN * OUTW;   // +524288
    float* traj   = xfinal + (size_t)BSZ * HID;        // +16384

    // workspace layout (bytes):
    //   Wsw  : 0          .. 33,554,432   (2^24 bf16)
    //   rbf0 : 33,554,432 .. +32,768
    //   rbf1 : 33,587,200 .. +32,768
    //   cnt  : 33,619,968 .. +4
    char* ws = (char*)d_ws;
    __hip_bfloat16* Wsw = (__hip_bfloat16*)ws;
    __hip_bfloat16* rbf0 = (__hip_bfloat16*)(ws + 33554432);
    __hip_bfloat16* rbf1 = (__hip_bfloat16*)(ws + 33587200);
    int* cnt = (int*)(ws + 33619968);

    hipMemsetAsync(cnt, 0, 4, stream);
    swizzle_kernel<<<8192, 256, 0, stream>>>(W, Wsw);
    init_kernel<<<64, 256, 0, stream>>>(x0, rbf0);

    persist_kernel<<<256, 256, 0, stream>>>(
        Wsw, w_hh, u, w_in_w, w_in_b, noise, x0,
        rbf0, rbf1, traj, xfinal, cnt);

    output_kernel<<<(BSZ * TLEN) / 8, 256, 0, stream>>>(traj, w_out_w, w_out_b, out);
}